// Round 1
// baseline (521.145 us; speedup 1.0000x reference)
//
#include <hip/hip_runtime.h>

typedef unsigned short u16;
typedef __attribute__((ext_vector_type(8))) short short8;   // 8 bf16 = 4 VGPRs (MFMA A/B frag)
typedef __attribute__((ext_vector_type(4))) float f32x4;    // MFMA C/D frag

#define T_SEQ 8192
#define DDIM 1024
#define BB 4
#define MM (BB * T_SEQ)      // 32768
#define NC 128               // chunks along T
#define CHUNK (T_SEQ / NC)   // 64
#define CHAINS (BB * DDIM)   // 4096
#define NT 16                // K tiles of 64 in the GEMM

// ---------- helpers ----------
__device__ __forceinline__ float bf_lo(unsigned p) {
    union { unsigned u; float f; } v; v.u = p << 16; return v.f;
}
__device__ __forceinline__ float bf_hi(unsigned p) {
    union { unsigned u; float f; } v; v.u = p & 0xffff0000u; return v.f;
}
__device__ __forceinline__ float bf_u16(u16 p) {
    union { unsigned u; float f; } v; v.u = ((unsigned)p) << 16; return v.f;
}
__device__ __forceinline__ u16 f2bf(float f) {
    union { unsigned u; float f; } v; v.f = f;
    unsigned r = v.u + 0x7fffu + ((v.u >> 16) & 1u);   // RNE
    return (u16)(r >> 16);
}
__device__ __forceinline__ float sigm(float z) {
    return __builtin_amdgcn_rcpf(1.0f + __expf(-z));
}
__device__ __forceinline__ void gld16(const u16* g, u16* l) {
    __builtin_amdgcn_global_load_lds((const __attribute__((address_space(1))) void*)g,
                                     (__attribute__((address_space(3))) void*)l, 16, 0, 0);
}

// ---------- K1: fused fp32 -> bf16 convert for x, W_in, W_gate ----------
#define N4X (MM * DDIM / 4)      // 8388608 float4s
#define N4W (DDIM * DDIM / 4)    // 262144 float4s
__global__ __launch_bounds__(256) void cvt_all(const float* __restrict__ x,
                                               const float* __restrict__ Wi,
                                               const float* __restrict__ Wg,
                                               u16* __restrict__ Xb,
                                               u16* __restrict__ Wib,
                                               u16* __restrict__ Wgb) {
    int i = blockIdx.x * 256 + threadIdx.x;   // global float4 index
    const float* src; u16* dst; int j;
    if (i < N4X)            { src = x;  dst = Xb;  j = i; }
    else if (i < N4X + N4W) { src = Wi; dst = Wib; j = i - N4X; }
    else                    { src = Wg; dst = Wgb; j = i - N4X - N4W; }
    float4 v = ((const float4*)src)[j];
    ushort4 o;
    o.x = f2bf(v.x); o.y = f2bf(v.y); o.z = f2bf(v.z); o.w = f2bf(v.w);
    ((ushort4*)dst)[j] = o;
}

// ---------- K2: fused bf16 GEMM + gating epilogue (8-phase / counted-vmcnt) ----------
// 512 threads = 8 waves as WARPS_M=2 x WARPS_N=4. Virtual 256x256 tile:
// N-cols 0-127 = W_in cols (IG), 128-255 = W_gate cols (RG). Per-wave 128x64
// output -> acc[8][4]. BK=64 split in two kk-halves; LDS double-buffered
// (128 KB). Staging: global_load_lds w=16, 8 rounds/tile (A:kh,rowhalf x4;
// B:kh,gate x4), 2 rounds/phase, counted s_waitcnt vmcnt(4) twice per tile
// (never 0 in main loop). XOR-swizzle c8^=(row>>1)&3 applied on the GLOBAL
// source (linear LDS dest, rule #21) and on reads -> conflict-free b128.
// Epilogue identical numerics to prior kernel; s-exchange in reused LDS.

#define MFMA_ROW(i_, av)                                                              \
    acc[i_][0] = __builtin_amdgcn_mfma_f32_16x16x32_bf16(av, b0, acc[i_][0], 0, 0, 0); \
    acc[i_][1] = __builtin_amdgcn_mfma_f32_16x16x32_bf16(av, b1, acc[i_][1], 0, 0, 0); \
    acc[i_][2] = __builtin_amdgcn_mfma_f32_16x16x32_bf16(av, b2, acc[i_][2], 0, 0, 0); \
    acc[i_][3] = __builtin_amdgcn_mfma_f32_16x16x32_bf16(av, b3, acc[i_][3], 0, 0, 0);

#define MFMA_Q(ib) MFMA_ROW((ib)+0, a0) MFMA_ROW((ib)+1, a1) MFMA_ROW((ib)+2, a2) MFMA_ROW((ib)+3, a3)

#define PH_TAIL(IB)                                          \
    __builtin_amdgcn_s_barrier();                            \
    asm volatile("s_waitcnt lgkmcnt(0)" ::: "memory");       \
    __builtin_amdgcn_sched_barrier(0);                       \
    __builtin_amdgcn_s_setprio(1);                           \
    MFMA_Q(IB)                                               \
    __builtin_amdgcn_s_setprio(0);                           \
    __builtin_amdgcn_s_barrier();                            \
    __builtin_amdgcn_sched_barrier(0);

// staging: A round (buf,kh,rb) / B round (buf,kh,hf); t_ = K-tile index
#define STA(buf, kh, rb, t_) gld16(gA + (size_t)(t_)*64 + (kh)*32 + (size_t)(rb)*128*DDIM, \
                                   &lds[(((buf)*2 + (kh))*1024 + (rb)*512 + tid)*8])
#define STB(buf, kh, hf, t_) gld16(((hf) ? gBg : gBi) + (size_t)(t_)*64 + (kh)*32,          \
                                   &lds[32768 + (((buf)*2 + (kh))*1024 + (hf)*512 + tid)*8])

// reads (swizzled): row stride = 4 chunks of 16B = 32 u16
#define LDA(kk, i) (*(const short8*)&lds[((cur*2 + (kk))*256 + arow0 + (i)*16)*32 + aoff])
#define LDB(kk, j) (*(const short8*)&lds[32768 + ((cur*2 + (kk))*256 + brow0 + (j)*16)*32 + aoff])

__global__ __launch_bounds__(512, 2)
void gemm_fused(const u16* __restrict__ X, const u16* __restrict__ Wi,
                const u16* __restrict__ Wg, const float* __restrict__ b_in,
                const float* __restrict__ b_gate, const float* __restrict__ lam,
                u16* __restrict__ Sg, u16* __restrict__ XBg) {
    const int bid = blockIdx.x;         // 0..1023
    const int xcd = bid & 7;
    const int r = bid >> 3;             // 0..127
    const int n_tile = r & 7;           // N fastest within an XCD
    const int m_tile = xcd * 16 + (r >> 3);
    const int tN0 = n_tile * 128;
    const int tM0 = m_tile * 256;

    const int tid = threadIdx.x;
    const int lane = tid & 63;
    const int w = tid >> 6;             // 0..7
    const int wm = w >> 2;              // 0..1 (M half)
    const int wn = w & 3;               // 0..3
    const int gate = wn >> 1;           // 0: IG, 1: RG
    const int wn_sub = wn & 1;

    __shared__ u16 lds[65536];          // 128KB: A [0,32768), B [32768,65536)

    // staging source pointers (per-thread, pre-swizzled column chunk)
    const int srow = tid >> 2;                          // 0..127
    const int c8log = (tid & 3) ^ ((tid >> 3) & 3);     // inverse swizzle on source
    const u16* gA  = X  + (size_t)(tM0 + srow) * DDIM + c8log * 8;
    const u16* gBi = Wi + (size_t)(tN0 + srow) * DDIM + c8log * 8;
    const u16* gBg = Wg + (size_t)(tN0 + srow) * DDIM + c8log * 8;

    // read-side constants
    const int lm = lane & 15;
    const int aoff = (((lane >> 4) ^ ((lm >> 1) & 3))) * 8;  // swizzled chunk, lane-only
    const int arow0 = wm * 128 + lm;                 // + i*16
    const int brow0 = gate * 128 + wn_sub * 64 + lm; // + j*16

    f32x4 acc[8][4] = {};
    short8 a0, a1, a2, a3, b0, b1, b2, b3;

    // ---- prologue: stage tile 0 (A0,A1,B0,B1 then A2,A3,B2,B3) ----
    STA(0, 0, 0, 0); STA(0, 0, 1, 0); STB(0, 0, 0, 0); STB(0, 0, 1, 0);
    STA(0, 1, 0, 0); STA(0, 1, 1, 0); STB(0, 1, 0, 0); STB(0, 1, 1, 0);
    asm volatile("s_waitcnt vmcnt(4)" ::: "memory");   // kh0 rounds landed
    __builtin_amdgcn_s_barrier();
    __builtin_amdgcn_sched_barrier(0);

    // ---- main loop: tiles 0..NT-2, staging tile t+1 into buffer cur^1 ----
    for (int t = 0; t < NT - 1; ++t) {
        const int cur = t & 1, nb = cur ^ 1, tn = t + 1;
        // P0: kk0, rows 0-3 (+ all B kk0)
        b0 = LDB(0, 0); b1 = LDB(0, 1); b2 = LDB(0, 2); b3 = LDB(0, 3);
        a0 = LDA(0, 0); a1 = LDA(0, 1); a2 = LDA(0, 2); a3 = LDA(0, 3);
        STA(nb, 0, 0, tn); STA(nb, 0, 1, tn);
        PH_TAIL(0)
        // P1: kk0, rows 4-7
        a0 = LDA(0, 4); a1 = LDA(0, 5); a2 = LDA(0, 6); a3 = LDA(0, 7);
        STB(nb, 0, 0, tn); STB(nb, 0, 1, tn);
        asm volatile("s_waitcnt vmcnt(4)" ::: "memory");   // cert t's kh1 rounds
        PH_TAIL(4)
        // P2: kk1, rows 0-3
        b0 = LDB(1, 0); b1 = LDB(1, 1); b2 = LDB(1, 2); b3 = LDB(1, 3);
        a0 = LDA(1, 0); a1 = LDA(1, 1); a2 = LDA(1, 2); a3 = LDA(1, 3);
        STA(nb, 1, 0, tn); STA(nb, 1, 1, tn);
        PH_TAIL(0)
        // P3: kk1, rows 4-7
        a0 = LDA(1, 4); a1 = LDA(1, 5); a2 = LDA(1, 6); a3 = LDA(1, 7);
        STB(nb, 1, 0, tn); STB(nb, 1, 1, tn);
        asm volatile("s_waitcnt vmcnt(4)" ::: "memory");   // cert t+1's kh0 rounds
        PH_TAIL(4)
    }
    // ---- peeled last tile (buffer 1, no staging; one-time drain) ----
    {
        const int cur = (NT - 1) & 1;
        b0 = LDB(0, 0); b1 = LDB(0, 1); b2 = LDB(0, 2); b3 = LDB(0, 3);
        a0 = LDA(0, 0); a1 = LDA(0, 1); a2 = LDA(0, 2); a3 = LDA(0, 3);
        PH_TAIL(0)
        a0 = LDA(0, 4); a1 = LDA(0, 5); a2 = LDA(0, 6); a3 = LDA(0, 7);
        asm volatile("s_waitcnt vmcnt(0)" ::: "memory");
        PH_TAIL(4)
        b0 = LDB(1, 0); b1 = LDB(1, 1); b2 = LDB(1, 2); b3 = LDB(1, 3);
        a0 = LDA(1, 0); a1 = LDA(1, 1); a2 = LDA(1, 2); a3 = LDA(1, 3);
        PH_TAIL(0)
        a0 = LDA(1, 4); a1 = LDA(1, 5); a2 = LDA(1, 6); a3 = LDA(1, 7);
        PH_TAIL(4)
    }

    // ---- epilogue: C/D layout col=lane&15, row=(lane>>4)*4+rr ----
    // RG waves write s (bf16) to global + LDS exchange; IG waves consume.
    const int pair = wm * 2 + wn_sub;   // 0..3, pairs IG<->RG
    const int r0 = (lane >> 4) << 2;
    const int cb = lane & 15;
    if (gate) {                          // RG: s = nsp*sigm(rg)
#pragma unroll
        for (int j = 0; j < 4; ++j) {
            const int colg = tN0 + wn_sub * 64 + j * 16 + cb;
            const float bj = b_gate[colg];
            const float nsp = -8.0f * log1pf(__expf(lam[colg]));
#pragma unroll
            for (int i = 0; i < 8; ++i) {
                const int rowb = tM0 + wm * 128 + i * 16 + r0;
#pragma unroll
                for (int rr = 0; rr < 4; ++rr) {
                    float s = nsp * sigm(acc[i][j][rr] + bj);
                    u16 sb = f2bf(s);
                    Sg[(size_t)(rowb + rr) * DDIM + colg] = sb;
                    lds[((pair * 8 + i) * 16 + j * 4 + rr) * 64 + lane] = sb;
                }
            }
        }
    }
    asm volatile("s_waitcnt lgkmcnt(0)" ::: "memory");
    __builtin_amdgcn_s_barrier();
    __builtin_amdgcn_sched_barrier(0);
    if (!gate) {                         // IG: xb = beta*sigm(ig)*x
#pragma unroll
        for (int j = 0; j < 4; ++j) {
            const int colg = tN0 + wn_sub * 64 + j * 16 + cb;
            const float bj = b_in[colg];
#pragma unroll
            for (int i = 0; i < 8; ++i) {
                const int rowb = tM0 + wm * 128 + i * 16 + r0;
#pragma unroll
                for (int rr = 0; rr < 4; ++rr) {
                    float s = bf_u16(lds[((pair * 8 + i) * 16 + j * 4 + rr) * 64 + lane]);
                    float a2v = __expf(2.0f * s);
                    float be = sqrtf(1.0f - a2v + 1e-6f);
                    float p = sigm(acc[i][j][rr] + bj);
                    float xv = bf_u16(X[(size_t)(rowb + rr) * DDIM + colg]);
                    XBg[(size_t)(rowb + rr) * DDIM + colg] = f2bf(be * p * xv);
                }
            }
        }
    }
}

// ---------- K3: pass1 — per-chunk aggregates (light: 1 exp + 2 fma / elem) ----------
__global__ __launch_bounds__(256)
void scan_pass1(const u16* __restrict__ S, const u16* __restrict__ XB,
                float* __restrict__ AggA, float* __restrict__ AggB) {
    const int c = blockIdx.x, dblk = blockIdx.y, bq = blockIdx.z;
    const int d0 = dblk * 512 + threadIdx.x * 2;
    size_t base = ((size_t)(bq * T_SEQ + c * CHUNK)) * DDIM + d0;

    float A0 = 1.0f, B0 = 0.0f, A1 = 1.0f, B1 = 0.0f;
#pragma unroll 8
    for (int t = 0; t < CHUNK; t++) {
        unsigned sp = *(const unsigned*)(S + base);
        unsigned xp = *(const unsigned*)(XB + base);
        float a0 = __expf(bf_lo(sp));
        float a1 = __expf(bf_hi(sp));
        B0 = fmaf(a0, B0, bf_lo(xp)); A0 *= a0;
        B1 = fmaf(a1, B1, bf_hi(xp)); A1 *= a1;
        base += DDIM;
    }
    const int chain = bq * DDIM + d0;
    float2 av; av.x = A0; av.y = A1;
    float2 bv; bv.x = B0; bv.y = B1;
    *(float2*)(AggA + (size_t)c * CHAINS + chain) = av;
    *(float2*)(AggB + (size_t)c * CHAINS + chain) = bv;
}

// ---------- K4: pass2 — serial scan over NC chunk aggregates per chain ----------
__global__ __launch_bounds__(256)
void scan_pass2(const float* __restrict__ AggA, const float* __restrict__ AggB,
                float* __restrict__ H0) {
    const int chain = blockIdx.x * 256 + threadIdx.x;   // 4096 chains
    float p = 0.0f;
#pragma unroll 8
    for (int c = 0; c < NC; c++) {
        H0[(size_t)c * CHAINS + chain] = p;
        p = AggA[(size_t)c * CHAINS + chain] * p + AggB[(size_t)c * CHAINS + chain];
    }
}

// ---------- K5: pass3 — apply chunk prefix, write h ----------
__global__ __launch_bounds__(256)
void scan_pass3(const u16* __restrict__ S, const u16* __restrict__ XB,
                const float* __restrict__ H0, float* __restrict__ out) {
    const int c = blockIdx.x, dblk = blockIdx.y, bq = blockIdx.z;
    const int d0 = dblk * 512 + threadIdx.x * 2;
    size_t base = ((size_t)(bq * T_SEQ + c * CHUNK)) * DDIM + d0;
    const int chain = bq * DDIM + d0;

    float2 h = *(const float2*)(H0 + (size_t)c * CHAINS + chain);
#pragma unroll 8
    for (int t = 0; t < CHUNK; t++) {
        unsigned sp = *(const unsigned*)(S + base);
        unsigned xp = *(const unsigned*)(XB + base);
        float a0 = __expf(bf_lo(sp));
        float a1 = __expf(bf_hi(sp));
        h.x = fmaf(a0, h.x, bf_lo(xp));
        h.y = fmaf(a1, h.y, bf_hi(xp));
        *(float2*)(out + base) = h;
        base += DDIM;
    }
}

// ---------- launch ----------
extern "C" void kernel_launch(void* const* d_in, const int* in_sizes, int n_in,
                              void* d_out, int out_size, void* d_ws, size_t ws_size,
                              hipStream_t stream) {
    const float* x   = (const float*)d_in[0];
    const float* Win = (const float*)d_in[1];
    const float* bin = (const float*)d_in[2];
    const float* Wg  = (const float*)d_in[3];
    const float* bg  = (const float*)d_in[4];
    const float* lam = (const float*)d_in[5];
    float* out = (float*)d_out;

    // ws layout (MiB): Wi_bf 0..2, Wg_bf 2..4, S 4..68, XB 68..132,
    // AggA 132..134, AggB 134..136, H0 136..138  (= 138 MiB)
    char* w = (char*)d_ws;
    u16* Wi_bf  = (u16*)(w);
    u16* Wg_bf  = (u16*)(w + (size_t)(2) * 1024 * 1024);
    u16* Sg     = (u16*)(w + (size_t)(4) * 1024 * 1024);
    u16* XBg    = (u16*)(w + (size_t)(68) * 1024 * 1024);
    float* AggA = (float*)(w + (size_t)(132) * 1024 * 1024);
    float* AggB = (float*)(w + (size_t)(134) * 1024 * 1024);
    float* H0   = (float*)(w + (size_t)(136) * 1024 * 1024);

    // x_bf16 staged in first 64 MiB of d_out (read by GEMM main loop AND
    // epilogue; dead after GEMM; pass3 then overwrites d_out with h)
    u16* Xbf = (u16*)d_out;

    // K1: one fused convert (x + both W)
    cvt_all<<<dim3((N4X + 2 * N4W) / 256), dim3(256), 0, stream>>>(
        x, Win, Wg, Xbf, Wi_bf, Wg_bf);

    // K2: fused gate GEMM + gating epilogue, 8-phase counted-vmcnt schedule
    gemm_fused<<<dim3((DDIM / 128) * (MM / 256)), dim3(512), 0, stream>>>(
        Xbf, Wi_bf, Wg_bf, bin, bg, lam, Sg, XBg);

    // K3-K5: chunked scan over compact bf16 (S, XB)
    scan_pass1<<<dim3(NC, 2, BB), dim3(256), 0, stream>>>(Sg, XBg, AggA, AggB);
    scan_pass2<<<dim3(CHAINS / 256), dim3(256), 0, stream>>>(AggA, AggB, H0);
    scan_pass3<<<dim3(NC, 2, BB), dim3(256), 0, stream>>>(Sg, XBg, H0, out);
}

// Round 2
// 477.417 us; speedup vs baseline: 1.0916x; 1.0916x over previous
//
#include <hip/hip_runtime.h>

typedef unsigned short u16;
typedef __attribute__((ext_vector_type(8))) short short8;   // 8 bf16 = 4 VGPRs (MFMA A/B frag)
typedef __attribute__((ext_vector_type(4))) float f32x4;    // MFMA C/D frag

#define T_SEQ 8192
#define DDIM 1024
#define BB 4
#define MM (BB * T_SEQ)      // 32768
#define NC 128               // chunks along T
#define CHUNK (T_SEQ / NC)   // 64
#define CHAINS (BB * DDIM)   // 4096
#define NT 16                // K tiles of 64 in the GEMM

// ---------- helpers ----------
__device__ __forceinline__ float bf_lo(unsigned p) {
    union { unsigned u; float f; } v; v.u = p << 16; return v.f;
}
__device__ __forceinline__ float bf_hi(unsigned p) {
    union { unsigned u; float f; } v; v.u = p & 0xffff0000u; return v.f;
}
__device__ __forceinline__ float bf_u16(u16 p) {
    union { unsigned u; float f; } v; v.u = ((unsigned)p) << 16; return v.f;
}
__device__ __forceinline__ u16 f2bf(float f) {
    union { unsigned u; float f; } v; v.f = f;
    unsigned r = v.u + 0x7fffu + ((v.u >> 16) & 1u);   // RNE
    return (u16)(r >> 16);
}
__device__ __forceinline__ float sigm(float z) {
    return __builtin_amdgcn_rcpf(1.0f + __expf(-z));
}
__device__ __forceinline__ void gld16(const u16* g, u16* l) {
    __builtin_amdgcn_global_load_lds((const __attribute__((address_space(1))) void*)g,
                                     (__attribute__((address_space(3))) void*)l, 16, 0, 0);
}

// ---------- K1: fused fp32 -> bf16 convert for x, W_in, W_gate ----------
#define N4X (MM * DDIM / 4)      // 8388608 float4s
#define N4W (DDIM * DDIM / 4)    // 262144 float4s
__global__ __launch_bounds__(256) void cvt_all(const float* __restrict__ x,
                                               const float* __restrict__ Wi,
                                               const float* __restrict__ Wg,
                                               u16* __restrict__ Xb,
                                               u16* __restrict__ Wib,
                                               u16* __restrict__ Wgb) {
    int i = blockIdx.x * 256 + threadIdx.x;   // global float4 index
    const float* src; u16* dst; int j;
    if (i < N4X)            { src = x;  dst = Xb;  j = i; }
    else if (i < N4X + N4W) { src = Wi; dst = Wib; j = i - N4X; }
    else                    { src = Wg; dst = Wgb; j = i - N4X - N4W; }
    float4 v = ((const float4*)src)[j];
    ushort4 o;
    o.x = f2bf(v.x); o.y = f2bf(v.y); o.z = f2bf(v.z); o.w = f2bf(v.w);
    ((ushort4*)dst)[j] = o;
}

// ---------- K2: fused bf16 GEMM + gating epilogue ----------
// 8 waves (2M x 4N), virtual 256x256 tile (N: cols 0-127 Wi, 128-255 Wg).
// Per-wave 128x64 -> acc[8][4]. BK=64 as 2 half-tiles of K=32; LDS 2x dbuf.
// Per half-tile phase: {12 ds_read_b128; 4 global_load_lds; vmcnt(4); BAR;
// setprio(1); 32 MFMA (compiler-staged lgkmcnt -> LDS service overlaps MFMA);
// setprio(0); BAR}. NO explicit lgkmcnt(0)/sched_barrier before MFMA: the
// plain-C++ ds_reads are tracked natively and the compiler emits fine-grained
// lgkmcnt(N) per consuming MFMA (m97) -- forcing a drain serialized LDS vs
// MFMA and capped MfmaUtil at 23% (R1 post-mortem).
// Epilogue: all waves dump s(bf16)/p(u16 fixed-point) to reused LDS with a
// bank-uniform XOR swizzle, then all 512 threads store Sg/XBg vectorized.

#define MROW(i_, av)                                                                   \
    acc[i_][0] = __builtin_amdgcn_mfma_f32_16x16x32_bf16(av, b0, acc[i_][0], 0, 0, 0); \
    acc[i_][1] = __builtin_amdgcn_mfma_f32_16x16x32_bf16(av, b1, acc[i_][1], 0, 0, 0); \
    acc[i_][2] = __builtin_amdgcn_mfma_f32_16x16x32_bf16(av, b2, acc[i_][2], 0, 0, 0); \
    acc[i_][3] = __builtin_amdgcn_mfma_f32_16x16x32_bf16(av, b3, acc[i_][3], 0, 0, 0);

#define MALL MROW(0, a0) MROW(1, a1) MROW(2, a2) MROW(3, a3) \
             MROW(4, a4) MROW(5, a5) MROW(6, a6) MROW(7, a7)

#define RDALL(kk)                                                            \
    b0 = LDB(kk, 0); b1 = LDB(kk, 1); b2 = LDB(kk, 2); b3 = LDB(kk, 3);      \
    a0 = LDA(kk, 0); a1 = LDA(kk, 1); a2 = LDA(kk, 2); a3 = LDA(kk, 3);      \
    a4 = LDA(kk, 4); a5 = LDA(kk, 5); a6 = LDA(kk, 6); a7 = LDA(kk, 7);

// staging: A round (buf,kh,rb) / B round (buf,kh,hf); t_ = K-tile index
#define STA(buf, kh, rb, t_) gld16(gA + (size_t)(t_)*64 + (kh)*32 + (size_t)(rb)*128*DDIM, \
                                   &lds[(((buf)*2 + (kh))*1024 + (rb)*512 + tid)*8])
#define STB(buf, kh, hf, t_) gld16(((hf) ? gBg : gBi) + (size_t)(t_)*64 + (kh)*32,          \
                                   &lds[32768 + (((buf)*2 + (kh))*1024 + (hf)*512 + tid)*8])

// reads (swizzled): row stride = 4 chunks of 16B = 32 u16
#define LDA(kk, i) (*(const short8*)&lds[((cur*2 + (kk))*256 + arow0 + (i)*16)*32 + aoff])
#define LDB(kk, j) (*(const short8*)&lds[32768 + ((cur*2 + (kk))*256 + brow0 + (j)*16)*32 + aoff])

__global__ __launch_bounds__(512, 2)
void gemm_fused(const u16* __restrict__ X, const u16* __restrict__ Wi,
                const u16* __restrict__ Wg, const float* __restrict__ b_in,
                const float* __restrict__ b_gate, const float* __restrict__ lam,
                u16* __restrict__ Sg, u16* __restrict__ XBg) {
    const int bid = blockIdx.x;         // 0..1023
    const int xcd = bid & 7;
    const int r = bid >> 3;             // 0..127
    const int n_tile = r & 7;           // N fastest within an XCD
    const int m_tile = xcd * 16 + (r >> 3);
    const int tN0 = n_tile * 128;
    const int tM0 = m_tile * 256;

    const int tid = threadIdx.x;
    const int lane = tid & 63;
    const int w = tid >> 6;             // 0..7
    const int wm = w >> 2;              // 0..1 (M half)
    const int wn = w & 3;               // 0..3
    const int gate = wn >> 1;           // 0: IG, 1: RG
    const int wn_sub = wn & 1;

    __shared__ u16 lds[65536];          // 128KB: A [0,32768), B [32768,65536)

    // staging source pointers (per-thread, pre-swizzled column chunk)
    const int srow = tid >> 2;                          // 0..127
    const int c8log = (tid & 3) ^ ((tid >> 3) & 3);     // inverse swizzle on source
    const u16* gA  = X  + (size_t)(tM0 + srow) * DDIM + c8log * 8;
    const u16* gBi = Wi + (size_t)(tN0 + srow) * DDIM + c8log * 8;
    const u16* gBg = Wg + (size_t)(tN0 + srow) * DDIM + c8log * 8;

    // read-side constants
    const int lm = lane & 15;
    const int aoff = (((lane >> 4) ^ ((lm >> 1) & 3))) * 8;  // swizzled chunk, lane-only
    const int arow0 = wm * 128 + lm;                 // + i*16
    const int brow0 = gate * 128 + wn_sub * 64 + lm; // + j*16

    f32x4 acc[8][4] = {};
    short8 a0, a1, a2, a3, a4, a5, a6, a7, b0, b1, b2, b3;

    // ---- prologue: stage tile 0 (kh0 rounds first) ----
    STA(0, 0, 0, 0); STA(0, 0, 1, 0); STB(0, 0, 0, 0); STB(0, 0, 1, 0);
    STA(0, 1, 0, 0); STA(0, 1, 1, 0); STB(0, 1, 0, 0); STB(0, 1, 1, 0);
    asm volatile("s_waitcnt vmcnt(4)" ::: "memory");   // kh0 rounds landed
    __builtin_amdgcn_s_barrier();

    // ---- main loop: 2 half-tile phases per K-tile, staging t+1 into cur^1 ----
    for (int t = 0; t < NT - 1; ++t) {
        const int cur = t & 1, nb = cur ^ 1, tn = t + 1;
        // HT0: kk0 (K 0-31)
        RDALL(0)
        STA(nb, 0, 0, tn); STA(nb, 0, 1, tn); STB(nb, 0, 0, tn); STB(nb, 0, 1, tn);
        asm volatile("s_waitcnt vmcnt(4)" ::: "memory");   // cert tile t kh1
        __builtin_amdgcn_s_barrier();
        __builtin_amdgcn_s_setprio(1);
        MALL
        __builtin_amdgcn_s_setprio(0);
        __builtin_amdgcn_s_barrier();
        // HT1: kk1 (K 32-63)
        RDALL(1)
        STA(nb, 1, 0, tn); STA(nb, 1, 1, tn); STB(nb, 1, 0, tn); STB(nb, 1, 1, tn);
        asm volatile("s_waitcnt vmcnt(4)" ::: "memory");   // cert tile t+1 kh0
        __builtin_amdgcn_s_barrier();
        __builtin_amdgcn_s_setprio(1);
        MALL
        __builtin_amdgcn_s_setprio(0);
        __builtin_amdgcn_s_barrier();
    }
    // ---- peeled last tile (no staging; single drain) ----
    {
        const int cur = (NT - 1) & 1;
        RDALL(0)
        asm volatile("s_waitcnt vmcnt(0)" ::: "memory");   // cert last kh1
        __builtin_amdgcn_s_barrier();
        __builtin_amdgcn_s_setprio(1);
        MALL
        __builtin_amdgcn_s_setprio(0);
        __builtin_amdgcn_s_barrier();
        RDALL(1)
        __builtin_amdgcn_s_setprio(1);
        MALL
        __builtin_amdgcn_s_setprio(0);
        __builtin_amdgcn_s_barrier();     // all LDS reads done -> safe to reuse
    }

    // ---- epilogue stage 1: dump per-acc values to LDS (XOR bank swizzle) ----
    // C/D layout: col=lane&15, row=(lane>>4)*4+rr. Local tile 256x128.
    // S region  lds[0,32768):      s  (bf16, == value the scan consumes)
    // P region  lds[32768,65536):  p  (u16 fixed-point /65535 -> err ~1e-5)
    const int r0 = (lane >> 4) << 2;
    const int cb = lane & 15;
    if (gate) {                          // RG waves: s = nsp*sigm(rg+b)
#pragma unroll
        for (int j = 0; j < 4; ++j) {
            const int colg = tN0 + wn_sub * 64 + j * 16 + cb;
            const int cl = wn_sub * 64 + j * 16 + cb;
            const float bj = b_gate[colg];
            const float nsp = -8.0f * log1pf(__expf(lam[colg]));
#pragma unroll
            for (int i = 0; i < 8; ++i) {
                const int rl0 = wm * 128 + i * 16 + r0;
#pragma unroll
                for (int rr = 0; rr < 4; ++rr) {
                    const int rl = rl0 + rr;
                    float s = nsp * sigm(acc[i][j][rr] + bj);
                    lds[rl * 128 + (cl ^ (((rl >> 2) & 7) << 4))] = f2bf(s);
                }
            }
        }
    } else {                             // IG waves: p = sigm(ig+b), fixed-point
#pragma unroll
        for (int j = 0; j < 4; ++j) {
            const int colg = tN0 + wn_sub * 64 + j * 16 + cb;
            const int cl = wn_sub * 64 + j * 16 + cb;
            const float bj = b_in[colg];
#pragma unroll
            for (int i = 0; i < 8; ++i) {
                const int rl0 = wm * 128 + i * 16 + r0;
#pragma unroll
                for (int rr = 0; rr < 4; ++rr) {
                    const int rl = rl0 + rr;
                    float p = sigm(acc[i][j][rr] + bj);
                    lds[32768 + rl * 128 + (cl ^ (((rl >> 2) & 7) << 4))] =
                        (u16)(p * 65535.0f + 0.5f);
                }
            }
        }
    }
    asm volatile("s_waitcnt lgkmcnt(0)" ::: "memory");
    __builtin_amdgcn_s_barrier();
    __builtin_amdgcn_sched_barrier(0);

    // ---- epilogue stage 2: vectorized combine + 16B stores ----
    // thread -> col-chunk cc (8 cols), rows rg0..rg0+7 (full 256x128 tile)
    const int cc = tid & 15;
    const int rg0 = (tid >> 4) * 8;
#pragma unroll
    for (int k = 0; k < 8; ++k) {
        const int rl = rg0 + k;
        const int ch = (cc ^ (((rl >> 2) & 7) << 1)) * 8;   // swizzled chunk base
        short8 sv = *(const short8*)&lds[rl * 128 + ch];
        short8 pv = *(const short8*)&lds[32768 + rl * 128 + ch];
        const size_t go = (size_t)(tM0 + rl) * DDIM + tN0 + cc * 8;
        short8 xv = *(const short8*)&X[go];
        short8 ov;
#pragma unroll
        for (int e = 0; e < 8; ++e) {
            float s = bf_u16((u16)sv[e]);
            float p = (float)((u16)pv[e]) * (1.0f / 65535.0f);
            float xf = bf_u16((u16)xv[e]);
            float be = sqrtf(1.0f - __expf(2.0f * s) + 1e-6f);
            ov[e] = (short)f2bf(be * p * xf);
        }
        *(short8*)&Sg[go] = sv;
        *(short8*)&XBg[go] = ov;
    }
}

// ---------- K3: pass1 — per-chunk aggregates (light: 1 exp + 2 fma / elem) ----------
__global__ __launch_bounds__(256)
void scan_pass1(const u16* __restrict__ S, const u16* __restrict__ XB,
                float* __restrict__ AggA, float* __restrict__ AggB) {
    const int c = blockIdx.x, dblk = blockIdx.y, bq = blockIdx.z;
    const int d0 = dblk * 512 + threadIdx.x * 2;
    size_t base = ((size_t)(bq * T_SEQ + c * CHUNK)) * DDIM + d0;

    float A0 = 1.0f, B0 = 0.0f, A1 = 1.0f, B1 = 0.0f;
#pragma unroll 8
    for (int t = 0; t < CHUNK; t++) {
        unsigned sp = *(const unsigned*)(S + base);
        unsigned xp = *(const unsigned*)(XB + base);
        float a0 = __expf(bf_lo(sp));
        float a1 = __expf(bf_hi(sp));
        B0 = fmaf(a0, B0, bf_lo(xp)); A0 *= a0;
        B1 = fmaf(a1, B1, bf_hi(xp)); A1 *= a1;
        base += DDIM;
    }
    const int chain = bq * DDIM + d0;
    float2 av; av.x = A0; av.y = A1;
    float2 bv; bv.x = B0; bv.y = B1;
    *(float2*)(AggA + (size_t)c * CHAINS + chain) = av;
    *(float2*)(AggB + (size_t)c * CHAINS + chain) = bv;
}

// ---------- K4: pass2 — serial scan over NC chunk aggregates per chain ----------
__global__ __launch_bounds__(256)
void scan_pass2(const float* __restrict__ AggA, const float* __restrict__ AggB,
                float* __restrict__ H0) {
    const int chain = blockIdx.x * 256 + threadIdx.x;   // 4096 chains
    float p = 0.0f;
#pragma unroll 8
    for (int c = 0; c < NC; c++) {
        H0[(size_t)c * CHAINS + chain] = p;
        p = AggA[(size_t)c * CHAINS + chain] * p + AggB[(size_t)c * CHAINS + chain];
    }
}

// ---------- K5: pass3 — apply chunk prefix, write h ----------
__global__ __launch_bounds__(256)
void scan_pass3(const u16* __restrict__ S, const u16* __restrict__ XB,
                const float* __restrict__ H0, float* __restrict__ out) {
    const int c = blockIdx.x, dblk = blockIdx.y, bq = blockIdx.z;
    const int d0 = dblk * 512 + threadIdx.x * 2;
    size_t base = ((size_t)(bq * T_SEQ + c * CHUNK)) * DDIM + d0;
    const int chain = bq * DDIM + d0;

    float2 h = *(const float2*)(H0 + (size_t)c * CHAINS + chain);
#pragma unroll 8
    for (int t = 0; t < CHUNK; t++) {
        unsigned sp = *(const unsigned*)(S + base);
        unsigned xp = *(const unsigned*)(XB + base);
        float a0 = __expf(bf_lo(sp));
        float a1 = __expf(bf_hi(sp));
        h.x = fmaf(a0, h.x, bf_lo(xp));
        h.y = fmaf(a1, h.y, bf_hi(xp));
        *(float2*)(out + base) = h;
        base += DDIM;
    }
}

// ---------- launch ----------
extern "C" void kernel_launch(void* const* d_in, const int* in_sizes, int n_in,
                              void* d_out, int out_size, void* d_ws, size_t ws_size,
                              hipStream_t stream) {
    const float* x   = (const float*)d_in[0];
    const float* Win = (const float*)d_in[1];
    const float* bin = (const float*)d_in[2];
    const float* Wg  = (const float*)d_in[3];
    const float* bg  = (const float*)d_in[4];
    const float* lam = (const float*)d_in[5];
    float* out = (float*)d_out;

    // ws layout (MiB): Wi_bf 0..2, Wg_bf 2..4, S 4..68, XB 68..132,
    // AggA 132..134, AggB 134..136, H0 136..138  (= 138 MiB)
    char* w = (char*)d_ws;
    u16* Wi_bf  = (u16*)(w);
    u16* Wg_bf  = (u16*)(w + (size_t)(2) * 1024 * 1024);
    u16* Sg     = (u16*)(w + (size_t)(4) * 1024 * 1024);
    u16* XBg    = (u16*)(w + (size_t)(68) * 1024 * 1024);
    float* AggA = (float*)(w + (size_t)(132) * 1024 * 1024);
    float* AggB = (float*)(w + (size_t)(134) * 1024 * 1024);
    float* H0   = (float*)(w + (size_t)(136) * 1024 * 1024);

    // x_bf16 staged in first 64 MiB of d_out (read by GEMM main loop AND
    // epilogue; dead after GEMM; pass3 then overwrites d_out with h)
    u16* Xbf = (u16*)d_out;

    // K1: one fused convert (x + both W)
    cvt_all<<<dim3((N4X + 2 * N4W) / 256), dim3(256), 0, stream>>>(
        x, Win, Wg, Xbf, Wi_bf, Wg_bf);

    // K2: fused gate GEMM + gating epilogue, 2-half-tile-phase schedule
    gemm_fused<<<dim3((DDIM / 128) * (MM / 256)), dim3(512), 0, stream>>>(
        Xbf, Wi_bf, Wg_bf, bin, bg, lam, Sg, XBg);

    // K3-K5: chunked scan over compact bf16 (S, XB)
    scan_pass1<<<dim3(NC, 2, BB), dim3(256), 0, stream>>>(Sg, XBg, AggA, AggB);
    scan_pass2<<<dim3(CHAINS / 256), dim3(256), 0, stream>>>(AggA, AggB, H0);
    scan_pass3<<<dim3(NC, 2, BB), dim3(256), 0, stream>>>(Sg, XBg, H0, out);
}

// Round 3
// 474.387 us; speedup vs baseline: 1.0986x; 1.0064x over previous
//
#include <hip/hip_runtime.h>

typedef unsigned short u16;
typedef __attribute__((ext_vector_type(8))) short short8;   // 8 bf16 = 4 VGPRs (MFMA A/B frag)
typedef __attribute__((ext_vector_type(4))) float f32x4;    // MFMA C/D frag

#define T_SEQ 8192
#define DDIM 1024
#define BB 4
#define MM (BB * T_SEQ)      // 32768
#define NC 128               // chunks along T
#define CHUNK (T_SEQ / NC)   // 64
#define CHAINS (BB * DDIM)   // 4096
#define NT 16                // K tiles of 64 in the GEMM
#define NHT 32               // half-tiles (K=32 each)

// ---------- helpers ----------
__device__ __forceinline__ float bf_lo(unsigned p) {
    union { unsigned u; float f; } v; v.u = p << 16; return v.f;
}
__device__ __forceinline__ float bf_hi(unsigned p) {
    union { unsigned u; float f; } v; v.u = p & 0xffff0000u; return v.f;
}
__device__ __forceinline__ float bf_u16(u16 p) {
    union { unsigned u; float f; } v; v.u = ((unsigned)p) << 16; return v.f;
}
__device__ __forceinline__ u16 f2bf(float f) {
    union { unsigned u; float f; } v; v.f = f;
    unsigned r = v.u + 0x7fffu + ((v.u >> 16) & 1u);   // RNE
    return (u16)(r >> 16);
}
__device__ __forceinline__ float sigm(float z) {
    return __builtin_amdgcn_rcpf(1.0f + __expf(-z));
}
__device__ __forceinline__ void gld16(const u16* g, u16* l) {
    __builtin_amdgcn_global_load_lds((const __attribute__((address_space(1))) void*)g,
                                     (__attribute__((address_space(3))) void*)l, 16, 0, 0);
}

// ---------- K1: fused fp32 -> bf16 convert for x, W_in, W_gate ----------
#define N4X (MM * DDIM / 4)      // 8388608 float4s
#define N4W (DDIM * DDIM / 4)    // 262144 float4s
__global__ __launch_bounds__(256) void cvt_all(const float* __restrict__ x,
                                               const float* __restrict__ Wi,
                                               const float* __restrict__ Wg,
                                               u16* __restrict__ Xb,
                                               u16* __restrict__ Wib,
                                               u16* __restrict__ Wgb) {
    int i = blockIdx.x * 256 + threadIdx.x;   // global float4 index
    const float* src; u16* dst; int j;
    if (i < N4X)            { src = x;  dst = Xb;  j = i; }
    else if (i < N4X + N4W) { src = Wi; dst = Wib; j = i - N4X; }
    else                    { src = Wg; dst = Wgb; j = i - N4X - N4W; }
    float4 v = ((const float4*)src)[j];
    ushort4 o;
    o.x = f2bf(v.x); o.y = f2bf(v.y); o.z = f2bf(v.z); o.w = f2bf(v.w);
    ((ushort4*)dst)[j] = o;
}

// ---------- K2: fused bf16 GEMM + gating epilogue ----------
// 8 waves (2M x 4N), virtual 256x256 tile (N: cols 0-127 Wi, 128-255 Wg).
// Per-wave 128x64 -> acc[8][4]. K split into 32 half-tiles (K=32); LDS is a
// RING OF 4 half-tile slots (4 x (16KB A + 16KB B) = 128 KB). Phase h:
// {vmcnt(8) certify slot h; barrier; 12 ds_read_b128 from slot h&3;
//  issue 4 global_load_lds for h+3 into slot (h+3)&3; 32 MFMA}.
// Prefetch slack = 3 phases (~3000 cyc) >> HBM latency — R2's 1-phase slack
// exposed the vmcnt wait each phase and capped MfmaUtil at 30%.
// vmcnt never 0 in main loop; tail drains 8 -> 4 -> 0.
// Epilogue: waves dump s(bf16)/p(u16 fixed-point) to reused LDS (XOR bank
// swizzle), then all 512 threads do vectorized combine + 16B global stores.

#define MROW(i_, av)                                                                   \
    acc[i_][0] = __builtin_amdgcn_mfma_f32_16x16x32_bf16(av, b0, acc[i_][0], 0, 0, 0); \
    acc[i_][1] = __builtin_amdgcn_mfma_f32_16x16x32_bf16(av, b1, acc[i_][1], 0, 0, 0); \
    acc[i_][2] = __builtin_amdgcn_mfma_f32_16x16x32_bf16(av, b2, acc[i_][2], 0, 0, 0); \
    acc[i_][3] = __builtin_amdgcn_mfma_f32_16x16x32_bf16(av, b3, acc[i_][3], 0, 0, 0);

#define MALL MROW(0, a0) MROW(1, a1) MROW(2, a2) MROW(3, a3) \
             MROW(4, a4) MROW(5, a5) MROW(6, a6) MROW(7, a7)

// ring-slot reads (swizzled): A slot = (h&3)*8192 u16, B at +32768
#define LDA_H(h_, i) (*(const short8*)&lds[((h_)&3)*8192 + (arow0 + (i)*16)*32 + aoff])
#define LDB_H(h_, j) (*(const short8*)&lds[32768 + ((h_)&3)*8192 + (brow0 + (j)*16)*32 + aoff])

#define RD_H(h_)                                                                       \
    b0 = LDB_H(h_, 0); b1 = LDB_H(h_, 1); b2 = LDB_H(h_, 2); b3 = LDB_H(h_, 3);        \
    a0 = LDA_H(h_, 0); a1 = LDA_H(h_, 1); a2 = LDA_H(h_, 2); a3 = LDA_H(h_, 3);        \
    a4 = LDA_H(h_, 4); a5 = LDA_H(h_, 5); a6 = LDA_H(h_, 6); a7 = LDA_H(h_, 7);

// staging for half-tile h_ (K offset = h_*32): A rounds rb=0/1, B halves hf=0/1
#define STA_H(h_, rb) gld16(gA + (size_t)(h_)*32 + (size_t)(rb)*128*DDIM,              \
                            &lds[((h_)&3)*8192 + (rb)*4096 + tid*8])
#define STB_H(h_, hf) gld16(((hf) ? gBg : gBi) + (size_t)(h_)*32,                      \
                            &lds[32768 + ((h_)&3)*8192 + (hf)*4096 + tid*8])
#define ST_H(h_) STA_H(h_, 0); STA_H(h_, 1); STB_H(h_, 0); STB_H(h_, 1);

__global__ __launch_bounds__(512, 2)
void gemm_fused(const u16* __restrict__ X, const u16* __restrict__ Wi,
                const u16* __restrict__ Wg, const float* __restrict__ b_in,
                const float* __restrict__ b_gate, const float* __restrict__ lam,
                u16* __restrict__ Sg, u16* __restrict__ XBg) {
    const int bid = blockIdx.x;         // 0..1023
    const int xcd = bid & 7;
    const int r = bid >> 3;             // 0..127
    const int n_tile = r & 7;           // N fastest within an XCD
    const int m_tile = xcd * 16 + (r >> 3);
    const int tN0 = n_tile * 128;
    const int tM0 = m_tile * 256;

    const int tid = threadIdx.x;
    const int lane = tid & 63;
    const int w = tid >> 6;             // 0..7
    const int wm = w >> 2;              // 0..1 (M half)
    const int wn = w & 3;               // 0..3
    const int gate = wn >> 1;           // 0: IG, 1: RG
    const int wn_sub = wn & 1;

    __shared__ u16 lds[65536];          // 128KB: A ring [0,32768), B ring [32768,65536)

    // staging source pointers (per-thread, pre-swizzled column chunk)
    const int srow = tid >> 2;                          // 0..127
    const int c8log = (tid & 3) ^ ((tid >> 3) & 3);     // inverse swizzle on source
    const u16* gA  = X  + (size_t)(tM0 + srow) * DDIM + c8log * 8;
    const u16* gBi = Wi + (size_t)(tN0 + srow) * DDIM + c8log * 8;
    const u16* gBg = Wg + (size_t)(tN0 + srow) * DDIM + c8log * 8;

    // read-side constants
    const int lm = lane & 15;
    const int aoff = (((lane >> 4) ^ ((lm >> 1) & 3))) * 8;  // swizzled chunk, lane-only
    const int arow0 = wm * 128 + lm;                 // + i*16
    const int brow0 = gate * 128 + wn_sub * 64 + lm; // + j*16

    f32x4 acc[8][4] = {};
    short8 a0, a1, a2, a3, a4, a5, a6, a7, b0, b1, b2, b3;

    // ---- prologue: stage half-tiles 0,1,2 (12 rounds in flight) ----
    ST_H(0) ST_H(1) ST_H(2)

    // ---- main loop: phase h computes slot h, stages h+3 ----
    for (int h = 0; h < NHT - 3; ++h) {
        asm volatile("s_waitcnt vmcnt(8)" ::: "memory");   // certify slot h landed
        __builtin_amdgcn_s_barrier();
        RD_H(h)
        ST_H(h + 3)
        __builtin_amdgcn_s_setprio(1);
        MALL
        __builtin_amdgcn_s_setprio(0);
    }
    // ---- tail: h = 29,30,31 (drain 8 -> 4 -> 0) ----
    {
        asm volatile("s_waitcnt vmcnt(8)" ::: "memory");
        __builtin_amdgcn_s_barrier();
        RD_H(29)
        __builtin_amdgcn_s_setprio(1);
        MALL
        __builtin_amdgcn_s_setprio(0);
    }
    {
        asm volatile("s_waitcnt vmcnt(4)" ::: "memory");
        __builtin_amdgcn_s_barrier();
        RD_H(30)
        __builtin_amdgcn_s_setprio(1);
        MALL
        __builtin_amdgcn_s_setprio(0);
    }
    {
        asm volatile("s_waitcnt vmcnt(0)" ::: "memory");
        __builtin_amdgcn_s_barrier();
        RD_H(31)
        __builtin_amdgcn_s_setprio(1);
        MALL
        __builtin_amdgcn_s_setprio(0);
    }
    __builtin_amdgcn_s_barrier();        // all LDS reads done -> safe to reuse

    // ---- epilogue stage 1: dump per-acc values to LDS (XOR bank swizzle) ----
    // C/D layout: col=lane&15, row=(lane>>4)*4+rr. Local tile 256x128.
    // S region  lds[0,32768):      s  (bf16, == value the scan consumes)
    // P region  lds[32768,65536):  p  (u16 fixed-point /65535 -> err ~1e-5)
    const int r0 = (lane >> 4) << 2;
    const int cb = lane & 15;
    if (gate) {                          // RG waves: s = nsp*sigm(rg+b)
#pragma unroll
        for (int j = 0; j < 4; ++j) {
            const int colg = tN0 + wn_sub * 64 + j * 16 + cb;
            const int cl = wn_sub * 64 + j * 16 + cb;
            const float bj = b_gate[colg];
            const float nsp = -8.0f * log1pf(__expf(lam[colg]));
#pragma unroll
            for (int i = 0; i < 8; ++i) {
                const int rl0 = wm * 128 + i * 16 + r0;
#pragma unroll
                for (int rr = 0; rr < 4; ++rr) {
                    const int rl = rl0 + rr;
                    float s = nsp * sigm(acc[i][j][rr] + bj);
                    lds[rl * 128 + (cl ^ (((rl >> 2) & 7) << 4))] = f2bf(s);
                }
            }
        }
    } else {                             // IG waves: p = sigm(ig+b), fixed-point
#pragma unroll
        for (int j = 0; j < 4; ++j) {
            const int colg = tN0 + wn_sub * 64 + j * 16 + cb;
            const int cl = wn_sub * 64 + j * 16 + cb;
            const float bj = b_in[colg];
#pragma unroll
            for (int i = 0; i < 8; ++i) {
                const int rl0 = wm * 128 + i * 16 + r0;
#pragma unroll
                for (int rr = 0; rr < 4; ++rr) {
                    const int rl = rl0 + rr;
                    float p = sigm(acc[i][j][rr] + bj);
                    lds[32768 + rl * 128 + (cl ^ (((rl >> 2) & 7) << 4))] =
                        (u16)(p * 65535.0f + 0.5f);
                }
            }
        }
    }
    asm volatile("s_waitcnt lgkmcnt(0)" ::: "memory");
    __builtin_amdgcn_s_barrier();
    __builtin_amdgcn_sched_barrier(0);

    // ---- epilogue stage 2: vectorized combine + 16B stores ----
    // thread -> col-chunk cc (8 cols), rows rg0..rg0+7 (full 256x128 tile)
    const int cc = tid & 15;
    const int rg0 = (tid >> 4) * 8;
#pragma unroll
    for (int k = 0; k < 8; ++k) {
        const int rl = rg0 + k;
        const int ch = (cc ^ (((rl >> 2) & 7) << 1)) * 8;   // swizzled chunk base
        short8 sv = *(const short8*)&lds[rl * 128 + ch];
        short8 pv = *(const short8*)&lds[32768 + rl * 128 + ch];
        const size_t go = (size_t)(tM0 + rl) * DDIM + tN0 + cc * 8;
        short8 xv = *(const short8*)&X[go];
        short8 ov;
#pragma unroll
        for (int e = 0; e < 8; ++e) {
            float s = bf_u16((u16)sv[e]);
            float p = (float)((u16)pv[e]) * (1.0f / 65535.0f);
            float xf = bf_u16((u16)xv[e]);
            float be = sqrtf(1.0f - __expf(2.0f * s) + 1e-6f);
            ov[e] = (short)f2bf(be * p * xf);
        }
        *(short8*)&Sg[go] = sv;
        *(short8*)&XBg[go] = ov;
    }
}

// ---------- K3: pass1 — per-chunk aggregates (light: 1 exp + 2 fma / elem) ----------
__global__ __launch_bounds__(256)
void scan_pass1(const u16* __restrict__ S, const u16* __restrict__ XB,
                float* __restrict__ AggA, float* __restrict__ AggB) {
    const int c = blockIdx.x, dblk = blockIdx.y, bq = blockIdx.z;
    const int d0 = dblk * 512 + threadIdx.x * 2;
    size_t base = ((size_t)(bq * T_SEQ + c * CHUNK)) * DDIM + d0;

    float A0 = 1.0f, B0 = 0.0f, A1 = 1.0f, B1 = 0.0f;
#pragma unroll 8
    for (int t = 0; t < CHUNK; t++) {
        unsigned sp = *(const unsigned*)(S + base);
        unsigned xp = *(const unsigned*)(XB + base);
        float a0 = __expf(bf_lo(sp));
        float a1 = __expf(bf_hi(sp));
        B0 = fmaf(a0, B0, bf_lo(xp)); A0 *= a0;
        B1 = fmaf(a1, B1, bf_hi(xp)); A1 *= a1;
        base += DDIM;
    }
    const int chain = bq * DDIM + d0;
    float2 av; av.x = A0; av.y = A1;
    float2 bv; bv.x = B0; bv.y = B1;
    *(float2*)(AggA + (size_t)c * CHAINS + chain) = av;
    *(float2*)(AggB + (size_t)c * CHAINS + chain) = bv;
}

// ---------- K4: pass2 — serial scan over NC chunk aggregates per chain ----------
__global__ __launch_bounds__(256)
void scan_pass2(const float* __restrict__ AggA, const float* __restrict__ AggB,
                float* __restrict__ H0) {
    const int chain = blockIdx.x * 256 + threadIdx.x;   // 4096 chains
    float p = 0.0f;
#pragma unroll 8
    for (int c = 0; c < NC; c++) {
        H0[(size_t)c * CHAINS + chain] = p;
        p = AggA[(size_t)c * CHAINS + chain] * p + AggB[(size_t)c * CHAINS + chain];
    }
}

// ---------- K5: pass3 — apply chunk prefix, write h ----------
__global__ __launch_bounds__(256)
void scan_pass3(const u16* __restrict__ S, const u16* __restrict__ XB,
                const float* __restrict__ H0, float* __restrict__ out) {
    const int c = blockIdx.x, dblk = blockIdx.y, bq = blockIdx.z;
    const int d0 = dblk * 512 + threadIdx.x * 2;
    size_t base = ((size_t)(bq * T_SEQ + c * CHUNK)) * DDIM + d0;
    const int chain = bq * DDIM + d0;

    float2 h = *(const float2*)(H0 + (size_t)c * CHAINS + chain);
#pragma unroll 8
    for (int t = 0; t < CHUNK; t++) {
        unsigned sp = *(const unsigned*)(S + base);
        unsigned xp = *(const unsigned*)(XB + base);
        float a0 = __expf(bf_lo(sp));
        float a1 = __expf(bf_hi(sp));
        h.x = fmaf(a0, h.x, bf_lo(xp));
        h.y = fmaf(a1, h.y, bf_hi(xp));
        *(float2*)(out + base) = h;
        base += DDIM;
    }
}

// ---------- launch ----------
extern "C" void kernel_launch(void* const* d_in, const int* in_sizes, int n_in,
                              void* d_out, int out_size, void* d_ws, size_t ws_size,
                              hipStream_t stream) {
    const float* x   = (const float*)d_in[0];
    const float* Win = (const float*)d_in[1];
    const float* bin = (const float*)d_in[2];
    const float* Wg  = (const float*)d_in[3];
    const float* bg  = (const float*)d_in[4];
    const float* lam = (const float*)d_in[5];
    float* out = (float*)d_out;

    // ws layout (MiB): Wi_bf 0..2, Wg_bf 2..4, S 4..68, XB 68..132,
    // AggA 132..134, AggB 134..136, H0 136..138  (= 138 MiB)
    char* w = (char*)d_ws;
    u16* Wi_bf  = (u16*)(w);
    u16* Wg_bf  = (u16*)(w + (size_t)(2) * 1024 * 1024);
    u16* Sg     = (u16*)(w + (size_t)(4) * 1024 * 1024);
    u16* XBg    = (u16*)(w + (size_t)(68) * 1024 * 1024);
    float* AggA = (float*)(w + (size_t)(132) * 1024 * 1024);
    float* AggB = (float*)(w + (size_t)(134) * 1024 * 1024);
    float* H0   = (float*)(w + (size_t)(136) * 1024 * 1024);

    // x_bf16 staged in first 64 MiB of d_out (read by GEMM main loop AND
    // epilogue; dead after GEMM; pass3 then overwrites d_out with h)
    u16* Xbf = (u16*)d_out;

    // K1: one fused convert (x + both W)
    cvt_all<<<dim3((N4X + 2 * N4W) / 256), dim3(256), 0, stream>>>(
        x, Win, Wg, Xbf, Wi_bf, Wg_bf);

    // K2: fused gate GEMM + gating epilogue, ring-4 deep-prefetch schedule
    gemm_fused<<<dim3((DDIM / 128) * (MM / 256)), dim3(512), 0, stream>>>(
        Xbf, Wi_bf, Wg_bf, bin, bg, lam, Sg, XBg);

    // K3-K5: chunked scan over compact bf16 (S, XB)
    scan_pass1<<<dim3(NC, 2, BB), dim3(256), 0, stream>>>(Sg, XBg, AggA, AggB);
    scan_pass2<<<dim3(CHAINS / 256), dim3(256), 0, stream>>>(AggA, AggB, H0);
    scan_pass3<<<dim3(NC, 2, BB), dim3(256), 0, stream>>>(Sg, XBg, H0, out);
}

// Round 4
// 466.995 us; speedup vs baseline: 1.1160x; 1.0158x over previous
//
#include <hip/hip_runtime.h>

typedef unsigned short u16;
typedef __attribute__((ext_vector_type(8))) short short8;   // 8 bf16 = 4 VGPRs (MFMA A/B frag)
typedef __attribute__((ext_vector_type(4))) float f32x4;    // MFMA C/D frag

#define T_SEQ 8192
#define DDIM 1024
#define BB 4
#define MM (BB * T_SEQ)      // 32768
#define NC 128               // chunks along T
#define CHUNK (T_SEQ / NC)   // 64
#define CHAINS (BB * DDIM)   // 4096
#define NHT 32               // half-tiles (K=32 each)

// ---------- helpers ----------
__device__ __forceinline__ float bf_lo(unsigned p) {
    union { unsigned u; float f; } v; v.u = p << 16; return v.f;
}
__device__ __forceinline__ float bf_hi(unsigned p) {
    union { unsigned u; float f; } v; v.u = p & 0xffff0000u; return v.f;
}
__device__ __forceinline__ float bf_u16(u16 p) {
    union { unsigned u; float f; } v; v.u = ((unsigned)p) << 16; return v.f;
}
__device__ __forceinline__ u16 f2bf(float f) {
    union { unsigned u; float f; } v; v.f = f;
    unsigned r = v.u + 0x7fffu + ((v.u >> 16) & 1u);   // RNE
    return (u16)(r >> 16);
}
__device__ __forceinline__ float sigm(float z) {
    return __builtin_amdgcn_rcpf(1.0f + __expf(-z));
}
__device__ __forceinline__ void gld16(const u16* g, u16* l) {
    __builtin_amdgcn_global_load_lds((const __attribute__((address_space(1))) void*)g,
                                     (__attribute__((address_space(3))) void*)l, 16, 0, 0);
}

// ---------- K1: fused fp32 -> bf16 convert for x, W_in, W_gate ----------
#define N4X (MM * DDIM / 4)      // 8388608 float4s
#define N4W (DDIM * DDIM / 4)    // 262144 float4s
__global__ __launch_bounds__(256) void cvt_all(const float* __restrict__ x,
                                               const float* __restrict__ Wi,
                                               const float* __restrict__ Wg,
                                               u16* __restrict__ Xb,
                                               u16* __restrict__ Wib,
                                               u16* __restrict__ Wgb) {
    int i = blockIdx.x * 256 + threadIdx.x;   // global float4 index
    const float* src; u16* dst; int j;
    if (i < N4X)            { src = x;  dst = Xb;  j = i; }
    else if (i < N4X + N4W) { src = Wi; dst = Wib; j = i - N4X; }
    else                    { src = Wg; dst = Wgb; j = i - N4X - N4W; }
    float4 v = ((const float4*)src)[j];
    ushort4 o;
    o.x = f2bf(v.x); o.y = f2bf(v.y); o.z = f2bf(v.z); o.w = f2bf(v.w);
    ((ushort4*)dst)[j] = o;
}

// ---------- K2: fused bf16 GEMM + gating epilogue (m201-style phase schedule) ----------
// 8 waves (2M x 4N), virtual 256x256 tile (N: cols 0-127 Wi, 128-255 Wg).
// Per-wave 128x64 -> acc[8][4]. K = 32 half-tiles of 32; LDS ring of 4 slots.
// Each half-tile = TWO phases of 16 MFMA (rows 0-3, rows 4-7); B-frags persist
// in registers across the pair. Phase: {ds_reads; 2 gld; [vmcnt]; barrier;
// lgkmcnt(0)+sched_barrier; setprio(1); 16 MFMA; setprio(0); barrier}.
// KEY (R3 post-mortem): per-wave lgkmcnt(0) AFTER the barrier -> waves release
// staggered as LDS serves their reads -> early waves' MFMA clusters overlap
// late waves' LDS service (m201's 62%-util mechanism). R3 serialized the full
// CU LDS drain against the MFMA burst (2800 cyc/phase = 1240 MFMA + 1150 LDS).
// vmcnt certification one PAIR ahead of consumption (in PHB of pair h certify
// slot h+1), so slot reads always follow a vmcnt+barrier from an earlier
// phase (cross-wave staging safety). Steady-state vmcnt(8), never 0 mid-loop.

#define MROW(i_, av)                                                                   \
    acc[i_][0] = __builtin_amdgcn_mfma_f32_16x16x32_bf16(av, b0, acc[i_][0], 0, 0, 0); \
    acc[i_][1] = __builtin_amdgcn_mfma_f32_16x16x32_bf16(av, b1, acc[i_][1], 0, 0, 0); \
    acc[i_][2] = __builtin_amdgcn_mfma_f32_16x16x32_bf16(av, b2, acc[i_][2], 0, 0, 0); \
    acc[i_][3] = __builtin_amdgcn_mfma_f32_16x16x32_bf16(av, b3, acc[i_][3], 0, 0, 0);

// reads (swizzled) from compile-time ring slot s_
#define LDA_S(s_, i) (*(const short8*)&lds[(s_)*8192 + (arow0 + (i)*16)*32 + aoff])
#define LDB_S(s_, j) (*(const short8*)&lds[32768 + (s_)*8192 + (brow0 + (j)*16)*32 + aoff])

// staging rounds into compile-time slot ds_, from half-tile index ht_ (runtime OK)
#define STA_S(ds_, ht_, rb) gld16(gA + (size_t)(ht_)*32 + (size_t)(rb)*128*DDIM,       \
                                  &lds[(ds_)*8192 + (rb)*4096 + tid*8])
#define STB_S(ds_, ht_, hf) gld16(((hf) ? gBg : gBi) + (size_t)(ht_)*32,               \
                                  &lds[32768 + (ds_)*8192 + (hf)*4096 + tid*8])

#define PHASE_A(s_, ds_, ht_, DOST)                                                    \
    b0 = LDB_S(s_, 0); b1 = LDB_S(s_, 1); b2 = LDB_S(s_, 2); b3 = LDB_S(s_, 3);        \
    a0 = LDA_S(s_, 0); a1 = LDA_S(s_, 1); a2 = LDA_S(s_, 2); a3 = LDA_S(s_, 3);        \
    if (DOST) { STA_S(ds_, ht_, 0); STA_S(ds_, ht_, 1); }                              \
    __builtin_amdgcn_s_barrier();                                                      \
    asm volatile("s_waitcnt lgkmcnt(0)" ::: "memory");                                 \
    __builtin_amdgcn_sched_barrier(0);                                                 \
    __builtin_amdgcn_s_setprio(1);                                                     \
    MROW(0, a0) MROW(1, a1) MROW(2, a2) MROW(3, a3)                                    \
    __builtin_amdgcn_s_setprio(0);                                                     \
    __builtin_amdgcn_s_barrier();

#define PHASE_B(s_, ds_, ht_, DOST, VMS)                                               \
    a0 = LDA_S(s_, 4); a1 = LDA_S(s_, 5); a2 = LDA_S(s_, 6); a3 = LDA_S(s_, 7);        \
    if (DOST) { STB_S(ds_, ht_, 0); STB_S(ds_, ht_, 1); }                              \
    asm volatile("s_waitcnt " VMS ::: "memory");                                       \
    __builtin_amdgcn_s_barrier();                                                      \
    asm volatile("s_waitcnt lgkmcnt(0)" ::: "memory");                                 \
    __builtin_amdgcn_sched_barrier(0);                                                 \
    __builtin_amdgcn_s_setprio(1);                                                     \
    MROW(4, a0) MROW(5, a1) MROW(6, a2) MROW(7, a3)                                    \
    __builtin_amdgcn_s_setprio(0);                                                     \
    __builtin_amdgcn_s_barrier();

#define PAIR(s_, ds_, ht_, DOST, VMS)                                                  \
    PHASE_A(s_, ds_, ht_, DOST)                                                        \
    PHASE_B(s_, ds_, ht_, DOST, VMS)

__global__ __launch_bounds__(512, 2)
void gemm_fused(const u16* __restrict__ X, const u16* __restrict__ Wi,
                const u16* __restrict__ Wg, const float* __restrict__ b_in,
                const float* __restrict__ b_gate, const float* __restrict__ lam,
                u16* __restrict__ Sg, u16* __restrict__ XBg) {
    const int bid = blockIdx.x;         // 0..1023
    const int xcd = bid & 7;
    const int r = bid >> 3;             // 0..127
    const int n_tile = r & 7;           // N fastest within an XCD
    const int m_tile = xcd * 16 + (r >> 3);
    const int tN0 = n_tile * 128;
    const int tM0 = m_tile * 256;

    const int tid = threadIdx.x;
    const int lane = tid & 63;
    const int w = tid >> 6;             // 0..7
    const int wm = w >> 2;              // 0..1 (M half)
    const int wn = w & 3;               // 0..3
    const int gate = wn >> 1;           // 0: IG, 1: RG
    const int wn_sub = wn & 1;

    __shared__ u16 lds[65536];          // 128KB: A ring [0,32768), B ring [32768,65536)

    // staging source pointers (per-thread, pre-swizzled column chunk)
    const int srow = tid >> 2;                          // 0..127
    const int c8log = (tid & 3) ^ ((tid >> 3) & 3);     // inverse swizzle on source
    const u16* gA  = X  + (size_t)(tM0 + srow) * DDIM + c8log * 8;
    const u16* gBi = Wi + (size_t)(tN0 + srow) * DDIM + c8log * 8;
    const u16* gBg = Wg + (size_t)(tN0 + srow) * DDIM + c8log * 8;

    // read-side constants
    const int lm = lane & 15;
    const int aoff = (((lane >> 4) ^ ((lm >> 1) & 3))) * 8;  // swizzled chunk, lane-only
    const int arow0 = wm * 128 + lm;                 // + i*16
    const int brow0 = gate * 128 + wn_sub * 64 + lm; // + j*16

    f32x4 acc[8][4] = {};
    short8 a0, a1, a2, a3, b0, b1, b2, b3;

    // ---- prologue: stage half-tiles 0,1,2 (12 rounds), certify slot 0 ----
    STA_S(0, 0, 0); STA_S(0, 0, 1); STB_S(0, 0, 0); STB_S(0, 0, 1);
    STA_S(1, 1, 0); STA_S(1, 1, 1); STB_S(1, 1, 0); STB_S(1, 1, 1);
    STA_S(2, 2, 0); STA_S(2, 2, 1); STB_S(2, 2, 0); STB_S(2, 2, 1);
    asm volatile("s_waitcnt vmcnt(8)" ::: "memory");   // slot 0 landed
    __builtin_amdgcn_s_barrier();

    // ---- main loop: pairs h = 4g..4g+3, stage h+3, certify h+1 ----
    for (int g = 0; g < 7; ++g) {
        const int hb = 4 * g;
        PAIR(0, 3, hb + 3, 1, "vmcnt(8)")
        PAIR(1, 0, hb + 4, 1, "vmcnt(8)")
        PAIR(2, 1, hb + 5, 1, "vmcnt(8)")
        PAIR(3, 2, hb + 6, 1, "vmcnt(8)")
    }
    // ---- tail: h = 28 (stage 31, cert 29), 29 (cert 30), 30 (cert 31), 31 ----
    PAIR(0, 3, 31, 1, "vmcnt(8)")
    PAIR(1, 0, 0, 0, "vmcnt(4)")
    PAIR(2, 0, 0, 0, "vmcnt(0)")
    PAIR(3, 0, 0, 0, "vmcnt(0)")
    // PHASE_B ends with a barrier: all slot reads drained -> LDS reusable

    // ---- epilogue stage 1: dump per-acc values to LDS (XOR bank swizzle) ----
    // C/D layout: col=lane&15, row=(lane>>4)*4+rr. Local tile 256x128.
    // S region  lds[0,32768):      s  (bf16, == value the scan consumes)
    // P region  lds[32768,65536):  p  (u16 fixed-point /65535 -> err ~1e-5)
    const int r0 = (lane >> 4) << 2;
    const int cb = lane & 15;
    if (gate) {                          // RG waves: s = nsp*sigm(rg+b)
#pragma unroll
        for (int j = 0; j < 4; ++j) {
            const int colg = tN0 + wn_sub * 64 + j * 16 + cb;
            const int cl = wn_sub * 64 + j * 16 + cb;
            const float bj = b_gate[colg];
            const float nsp = -8.0f * log1pf(__expf(lam[colg]));
#pragma unroll
            for (int i = 0; i < 8; ++i) {
                const int rl0 = wm * 128 + i * 16 + r0;
#pragma unroll
                for (int rr = 0; rr < 4; ++rr) {
                    const int rl = rl0 + rr;
                    float s = nsp * sigm(acc[i][j][rr] + bj);
                    lds[rl * 128 + (cl ^ (((rl >> 2) & 7) << 4))] = f2bf(s);
                }
            }
        }
    } else {                             // IG waves: p = sigm(ig+b), fixed-point
#pragma unroll
        for (int j = 0; j < 4; ++j) {
            const int colg = tN0 + wn_sub * 64 + j * 16 + cb;
            const int cl = wn_sub * 64 + j * 16 + cb;
            const float bj = b_in[colg];
#pragma unroll
            for (int i = 0; i < 8; ++i) {
                const int rl0 = wm * 128 + i * 16 + r0;
#pragma unroll
                for (int rr = 0; rr < 4; ++rr) {
                    const int rl = rl0 + rr;
                    float p = sigm(acc[i][j][rr] + bj);
                    lds[32768 + rl * 128 + (cl ^ (((rl >> 2) & 7) << 4))] =
                        (u16)(p * 65535.0f + 0.5f);
                }
            }
        }
    }
    asm volatile("s_waitcnt lgkmcnt(0)" ::: "memory");
    __builtin_amdgcn_s_barrier();
    __builtin_amdgcn_sched_barrier(0);

    // ---- epilogue stage 2: vectorized combine + 16B stores ----
    // thread -> col-chunk cc (8 cols), rows rg0..rg0+7 (full 256x128 tile)
    const int cc = tid & 15;
    const int rg0 = (tid >> 4) * 8;
#pragma unroll
    for (int k = 0; k < 8; ++k) {
        const int rl = rg0 + k;
        const int ch = (cc ^ (((rl >> 2) & 7) << 1)) * 8;   // swizzled chunk base
        short8 sv = *(const short8*)&lds[rl * 128 + ch];
        short8 pv = *(const short8*)&lds[32768 + rl * 128 + ch];
        const size_t go = (size_t)(tM0 + rl) * DDIM + tN0 + cc * 8;
        short8 xv = *(const short8*)&X[go];
        short8 ov;
#pragma unroll
        for (int e = 0; e < 8; ++e) {
            float s = bf_u16((u16)sv[e]);
            float p = (float)((u16)pv[e]) * (1.0f / 65535.0f);
            float xf = bf_u16((u16)xv[e]);
            float be = sqrtf(1.0f - __expf(2.0f * s) + 1e-6f);
            ov[e] = (short)f2bf(be * p * xf);
        }
        *(short8*)&Sg[go] = sv;
        *(short8*)&XBg[go] = ov;
    }
}

// ---------- K3: pass1 — per-chunk aggregates (light: 1 exp + 2 fma / elem) ----------
__global__ __launch_bounds__(256)
void scan_pass1(const u16* __restrict__ S, const u16* __restrict__ XB,
                float* __restrict__ AggA, float* __restrict__ AggB) {
    const int c = blockIdx.x, dblk = blockIdx.y, bq = blockIdx.z;
    const int d0 = dblk * 512 + threadIdx.x * 2;
    size_t base = ((size_t)(bq * T_SEQ + c * CHUNK)) * DDIM + d0;

    float A0 = 1.0f, B0 = 0.0f, A1 = 1.0f, B1 = 0.0f;
#pragma unroll 8
    for (int t = 0; t < CHUNK; t++) {
        unsigned sp = *(const unsigned*)(S + base);
        unsigned xp = *(const unsigned*)(XB + base);
        float a0 = __expf(bf_lo(sp));
        float a1 = __expf(bf_hi(sp));
        B0 = fmaf(a0, B0, bf_lo(xp)); A0 *= a0;
        B1 = fmaf(a1, B1, bf_hi(xp)); A1 *= a1;
        base += DDIM;
    }
    const int chain = bq * DDIM + d0;
    float2 av; av.x = A0; av.y = A1;
    float2 bv; bv.x = B0; bv.y = B1;
    *(float2*)(AggA + (size_t)c * CHAINS + chain) = av;
    *(float2*)(AggB + (size_t)c * CHAINS + chain) = bv;
}

// ---------- K4: pass2 — serial scan over NC chunk aggregates per chain ----------
__global__ __launch_bounds__(256)
void scan_pass2(const float* __restrict__ AggA, const float* __restrict__ AggB,
                float* __restrict__ H0) {
    const int chain = blockIdx.x * 256 + threadIdx.x;   // 4096 chains
    float p = 0.0f;
#pragma unroll 8
    for (int c = 0; c < NC; c++) {
        H0[(size_t)c * CHAINS + chain] = p;
        p = AggA[(size_t)c * CHAINS + chain] * p + AggB[(size_t)c * CHAINS + chain];
    }
}

// ---------- K5: pass3 — apply chunk prefix, write h ----------
__global__ __launch_bounds__(256)
void scan_pass3(const u16* __restrict__ S, const u16* __restrict__ XB,
                const float* __restrict__ H0, float* __restrict__ out) {
    const int c = blockIdx.x, dblk = blockIdx.y, bq = blockIdx.z;
    const int d0 = dblk * 512 + threadIdx.x * 2;
    size_t base = ((size_t)(bq * T_SEQ + c * CHUNK)) * DDIM + d0;
    const int chain = bq * DDIM + d0;

    float2 h = *(const float2*)(H0 + (size_t)c * CHAINS + chain);
#pragma unroll 8
    for (int t = 0; t < CHUNK; t++) {
        unsigned sp = *(const unsigned*)(S + base);
        unsigned xp = *(const unsigned*)(XB + base);
        float a0 = __expf(bf_lo(sp));
        float a1 = __expf(bf_hi(sp));
        h.x = fmaf(a0, h.x, bf_lo(xp));
        h.y = fmaf(a1, h.y, bf_hi(xp));
        *(float2*)(out + base) = h;
        base += DDIM;
    }
}

// ---------- launch ----------
extern "C" void kernel_launch(void* const* d_in, const int* in_sizes, int n_in,
                              void* d_out, int out_size, void* d_ws, size_t ws_size,
                              hipStream_t stream) {
    const float* x   = (const float*)d_in[0];
    const float* Win = (const float*)d_in[1];
    const float* bin = (const float*)d_in[2];
    const float* Wg  = (const float*)d_in[3];
    const float* bg  = (const float*)d_in[4];
    const float* lam = (const float*)d_in[5];
    float* out = (float*)d_out;

    // ws layout (MiB): Wi_bf 0..2, Wg_bf 2..4, S 4..68, XB 68..132,
    // AggA 132..134, AggB 134..136, H0 136..138  (= 138 MiB)
    char* w = (char*)d_ws;
    u16* Wi_bf  = (u16*)(w);
    u16* Wg_bf  = (u16*)(w + (size_t)(2) * 1024 * 1024);
    u16* Sg     = (u16*)(w + (size_t)(4) * 1024 * 1024);
    u16* XBg    = (u16*)(w + (size_t)(68) * 1024 * 1024);
    float* AggA = (float*)(w + (size_t)(132) * 1024 * 1024);
    float* AggB = (float*)(w + (size_t)(134) * 1024 * 1024);
    float* H0   = (float*)(w + (size_t)(136) * 1024 * 1024);

    // x_bf16 staged in first 64 MiB of d_out (read by GEMM main loop AND
    // epilogue; dead after GEMM; pass3 then overwrites d_out with h)
    u16* Xbf = (u16*)d_out;

    // K1: one fused convert (x + both W)
    cvt_all<<<dim3((N4X + 2 * N4W) / 256), dim3(256), 0, stream>>>(
        x, Win, Wg, Xbf, Wi_bf, Wg_bf);

    // K2: fused gate GEMM + gating epilogue, m201-style 16-MFMA phase schedule
    gemm_fused<<<dim3((DDIM / 128) * (MM / 256)), dim3(512), 0, stream>>>(
        Xbf, Wi_bf, Wg_bf, bin, bg, lam, Sg, XBg);

    // K3-K5: chunked scan over compact bf16 (S, XB)
    scan_pass1<<<dim3(NC, 2, BB), dim3(256), 0, stream>>>(Sg, XBg, AggA, AggB);
    scan_pass2<<<dim3(CHAINS / 256), dim3(256), 0, stream>>>(AggA, AggB, H0);
    scan_pass3<<<dim3(NC, 2, BB), dim3(256), 0, stream>>>(Sg, XBg, H0, out);
}